// Round 1
// baseline (3259.526 us; speedup 1.0000x reference)
//
#include <hip/hip_runtime.h>
#include <math.h>

#define BN_EPS 1e-5f

// ---------------- init: deg=1 (self loop), zero stats ----------------
__global__ void init_kernel(float* __restrict__ deg, float* __restrict__ stats, int N) {
    int i = blockIdx.x * blockDim.x + threadIdx.x;
    if (i < N) deg[i] = 1.0f;
    if (i < 1024) stats[i] = 0.0f;
}

// ---------------- degree over dst ----------------
__global__ void deg_kernel(const int* __restrict__ dst, float* __restrict__ deg, int E) {
    int e = blockIdx.x * blockDim.x + threadIdx.x;
    if (e < E)
        __hip_atomic_fetch_add(&deg[dst[e]], 1.0f, __ATOMIC_RELAXED, __HIP_MEMORY_SCOPE_AGENT);
}

__global__ void dinv_kernel(const float* __restrict__ deg, float* __restrict__ dinv, int N) {
    int i = blockIdx.x * blockDim.x + threadIdx.x;
    if (i < N) dinv[i] = rsqrtf(deg[i]);
}

// ---------------- Wc = proj_W @ W1  (256x256 @ 256x128) ----------------
__global__ void wc_kernel(const float* __restrict__ PW, const float* __restrict__ W1,
                          float* __restrict__ Wc) {
    int r = blockIdx.x;      // 0..255
    int c = threadIdx.x;     // 0..127
    float acc = 0.f;
    for (int k = 0; k < 256; ++k) acc = fmaf(PW[r * 256 + k], W1[k * 128 + c], acc);
    Wc[r * 128 + c] = acc;
}

// ---------------- bc = proj_b @ W1 ----------------
__global__ void bc_kernel(const float* __restrict__ pb, const float* __restrict__ W1,
                          float* __restrict__ bc) {
    int c = threadIdx.x;
    float acc = 0.f;
    for (int k = 0; k < 256; ++k) acc = fmaf(pb[k], W1[k * 128 + c], acc);
    bc[c] = acc;
}

// ---------------- H = op(X) @ W (+bias); op = optional BN1+ReLU ----------------
// block: 128 threads (one per out channel), 8 rows per block.
template <int K, bool BN>
__global__ __launch_bounds__(128) void gemv_kernel(
    const float* __restrict__ X, const float* __restrict__ W,
    const float* __restrict__ bias, float* __restrict__ H, int N,
    const float* __restrict__ gamma, const float* __restrict__ beta,
    const float* __restrict__ mu, const float* __restrict__ rstd)
{
    constexpr int ROWS = 8;
    constexpr int DOUT = 128;
    __shared__ float xs[ROWS][K];
    const int tid = threadIdx.x;
    const int r0 = blockIdx.x * ROWS;
    constexpr int K4 = K / 4;
    const float4* X4 = (const float4*)X;

    for (int i = tid; i < ROWS * K4; i += DOUT) {
        int row = i / K4;
        int k4  = i % K4;
        int gr  = r0 + row;
        float4 v = make_float4(0.f, 0.f, 0.f, 0.f);
        if (gr < N) v = X4[(size_t)gr * K4 + k4];
        if (BN) {
            int c = 4 * k4;
            float4 g  = *(const float4*)&gamma[c];
            float4 b  = *(const float4*)&beta[c];
            float4 m  = *(const float4*)&mu[c];
            float4 rs = *(const float4*)&rstd[c];
            v.x = fmaxf(fmaf(g.x * (v.x - m.x), rs.x, b.x), 0.f);
            v.y = fmaxf(fmaf(g.y * (v.y - m.y), rs.y, b.y), 0.f);
            v.z = fmaxf(fmaf(g.z * (v.z - m.z), rs.z, b.z), 0.f);
            v.w = fmaxf(fmaf(g.w * (v.w - m.w), rs.w, b.w), 0.f);
        }
        *(float4*)&xs[row][4 * k4] = v;
    }
    __syncthreads();

    float acc[ROWS];
#pragma unroll
    for (int r = 0; r < ROWS; ++r) acc[r] = 0.f;

    for (int k = 0; k < K; k += 4) {
        float4 xr[ROWS];
#pragma unroll
        for (int r = 0; r < ROWS; ++r) xr[r] = *(const float4*)&xs[r][k];
        float w0 = W[(k + 0) * DOUT + tid];
        float w1 = W[(k + 1) * DOUT + tid];
        float w2 = W[(k + 2) * DOUT + tid];
        float w3 = W[(k + 3) * DOUT + tid];
#pragma unroll
        for (int r = 0; r < ROWS; ++r) {
            acc[r] = fmaf(xr[r].x, w0, acc[r]);
            acc[r] = fmaf(xr[r].y, w1, acc[r]);
            acc[r] = fmaf(xr[r].z, w2, acc[r]);
            acc[r] = fmaf(xr[r].w, w3, acc[r]);
        }
    }

    float bb = bias ? bias[tid] : 0.f;
#pragma unroll
    for (int r = 0; r < ROWS; ++r) {
        int gr = r0 + r;
        if (gr < N) H[(size_t)gr * DOUT + tid] = acc[r] + bb;
    }
}

// ---------------- A[i] = H[i]*dinv[i]^2 + b (self-loop + bias init) ----------------
__global__ void agg_init_kernel(const float* __restrict__ H, const float* __restrict__ dinv,
                                const float* __restrict__ b, float* __restrict__ A, int N) {
    int i = blockIdx.x * blockDim.x + threadIdx.x;   // float4 index
    if (i >= N * 32) return;
    int r  = i >> 5;
    int c4 = i & 31;
    float di = dinv[r];
    float w  = di * di;
    float4 h  = ((const float4*)H)[i];
    float4 bb = ((const float4*)b)[c4];
    float4 o;
    o.x = fmaf(h.x, w, bb.x);
    o.y = fmaf(h.y, w, bb.y);
    o.z = fmaf(h.z, w, bb.z);
    o.w = fmaf(h.w, w, bb.w);
    ((float4*)A)[i] = o;
}

// ---------------- scatter-add edges: A[dst] += H[src]*dinv[src]*dinv[dst] ----------------
// one wave (64 lanes) per edge; 2 channels per lane.
__global__ __launch_bounds__(256) void agg_edge_kernel(
    const float* __restrict__ H, const int* __restrict__ src, const int* __restrict__ dst,
    const float* __restrict__ dinv, float* __restrict__ A, int E)
{
    int wave = blockIdx.x * (blockDim.x >> 6) + (threadIdx.x >> 6);
    int lane = threadIdx.x & 63;
    if (wave >= E) return;
    int s = src[wave], d = dst[wave];
    float norm = dinv[s] * dinv[d];
    float2 h2 = *(const float2*)&H[(size_t)s * 128 + lane * 2];
    float* out = &A[(size_t)d * 128 + lane * 2];
    __hip_atomic_fetch_add(out,     h2.x * norm, __ATOMIC_RELAXED, __HIP_MEMORY_SCOPE_AGENT);
    __hip_atomic_fetch_add(out + 1, h2.y * norm, __ATOMIC_RELAXED, __HIP_MEMORY_SCOPE_AGENT);
}

// ---------------- BN stats: per-column sum / sumsq ----------------
__global__ __launch_bounds__(256) void bn_stats_kernel(
    const float* __restrict__ A, float* __restrict__ sum, float* __restrict__ sq, int N)
{
    int c    = threadIdx.x & 127;
    int half = threadIdx.x >> 7;
    int r0   = blockIdx.x * 512;
    float s = 0.f, s2 = 0.f;
    for (int j = half; j < 512; j += 2) {
        int r = r0 + j;
        if (r < N) {
            float v = A[(size_t)r * 128 + c];
            s += v;
            s2 += v * v;
        }
    }
    __shared__ float ls[256], ls2[256];
    ls[threadIdx.x] = s;
    ls2[threadIdx.x] = s2;
    __syncthreads();
    if (threadIdx.x < 128) {
        float ts = ls[threadIdx.x] + ls[threadIdx.x + 128];
        float t2 = ls2[threadIdx.x] + ls2[threadIdx.x + 128];
        __hip_atomic_fetch_add(&sum[c], ts, __ATOMIC_RELAXED, __HIP_MEMORY_SCOPE_AGENT);
        __hip_atomic_fetch_add(&sq[c],  t2, __ATOMIC_RELAXED, __HIP_MEMORY_SCOPE_AGENT);
    }
}

__global__ void bn_final_kernel(const float* __restrict__ sum, const float* __restrict__ sq,
                                float* __restrict__ mu, float* __restrict__ rstd, int N) {
    int c = threadIdx.x;
    if (c < 128) {
        float m = sum[c] / (float)N;
        float v = sq[c] / (float)N - m * m;
        mu[c] = m;
        rstd[c] = rsqrtf(v + BN_EPS);
    }
}

// ---------------- final BN apply in-place on d_out ----------------
__global__ void bn_apply_kernel(float* __restrict__ A, const float* __restrict__ gamma,
                                const float* __restrict__ beta, const float* __restrict__ mu,
                                const float* __restrict__ rstd, int N) {
    int i = blockIdx.x * blockDim.x + threadIdx.x;   // float4 index
    if (i >= N * 32) return;
    int c4 = i & 31;
    float4 v  = ((float4*)A)[i];
    float4 g  = ((const float4*)gamma)[4 * 0 + c4];
    float4 b  = ((const float4*)beta)[c4];
    float4 m  = ((const float4*)mu)[c4];
    float4 rs = ((const float4*)rstd)[c4];
    v.x = fmaf(g.x * (v.x - m.x), rs.x, b.x);
    v.y = fmaf(g.y * (v.y - m.y), rs.y, b.y);
    v.z = fmaf(g.z * (v.z - m.z), rs.z, b.z);
    v.w = fmaf(g.w * (v.w - m.w), rs.w, b.w);
    ((float4*)A)[i] = v;
}

extern "C" void kernel_launch(void* const* d_in, const int* in_sizes, int n_in,
                              void* d_out, int out_size, void* d_ws, size_t ws_size,
                              hipStream_t stream) {
    const float* e_prev = (const float*)d_in[0];
    const int*   edges  = (const int*)d_in[1];
    const float* proj_W = (const float*)d_in[2];
    const float* proj_b = (const float*)d_in[3];
    const float* W1     = (const float*)d_in[4];
    const float* b1     = (const float*)d_in[5];
    const float* gamma1 = (const float*)d_in[6];
    const float* beta1  = (const float*)d_in[7];
    const float* W2     = (const float*)d_in[8];
    const float* b2     = (const float*)d_in[9];
    const float* gamma2 = (const float*)d_in[10];
    const float* beta2  = (const float*)d_in[11];
    float* out = (float*)d_out;

    const int N = in_sizes[0] / 256;
    const int E = in_sizes[1] / 2;
    const int* src = edges;
    const int* dst = edges + E;

    float* ws = (float*)d_ws;
    const size_t NH = (size_t)N * 128;
    float* H    = ws;            // [N,128] h1 then h2
    float* A1   = ws + NH;       // [N,128] layer-1 aggregate
    float* deg  = ws + 2 * NH;   // [N]
    float* dinv = deg + N;       // [N]
    float* Wc   = dinv + N;      // [256,128]
    float* bc   = Wc + 256 * 128;
    float* stats = bc + 128;     // 1024 floats of BN scratch
    float* sum1 = stats,       *sq1 = stats + 128, *mu1 = stats + 256, *rs1 = stats + 384;
    float* sum2 = stats + 512, *sq2 = stats + 640, *mu2 = stats + 768, *rs2 = stats + 896;

    init_kernel<<<(N + 255) / 256, 256, 0, stream>>>(deg, stats, N);
    deg_kernel<<<(E + 255) / 256, 256, 0, stream>>>(dst, deg, E);
    dinv_kernel<<<(N + 255) / 256, 256, 0, stream>>>(deg, dinv, N);
    wc_kernel<<<256, 128, 0, stream>>>(proj_W, W1, Wc);
    bc_kernel<<<1, 128, 0, stream>>>(proj_b, W1, bc);

    // layer 1: h1 = e_prev @ Wc + bc
    gemv_kernel<256, false><<<(N + 7) / 8, 128, 0, stream>>>(
        e_prev, Wc, bc, H, N, nullptr, nullptr, nullptr, nullptr);
    agg_init_kernel<<<(N * 32 + 255) / 256, 256, 0, stream>>>(H, dinv, b1, A1, N);
    agg_edge_kernel<<<(E + 3) / 4, 256, 0, stream>>>(H, src, dst, dinv, A1, E);
    bn_stats_kernel<<<(N + 511) / 512, 256, 0, stream>>>(A1, sum1, sq1, N);
    bn_final_kernel<<<1, 128, 0, stream>>>(sum1, sq1, mu1, rs1, N);

    // layer 2: h2 = relu(bn1(A1)) @ W2  (BN+ReLU fused into LDS load)
    gemv_kernel<128, true><<<(N + 7) / 8, 128, 0, stream>>>(
        A1, W2, nullptr, H, N, gamma1, beta1, mu1, rs1);
    agg_init_kernel<<<(N * 32 + 255) / 256, 256, 0, stream>>>(H, dinv, b2, out, N);
    agg_edge_kernel<<<(E + 3) / 4, 256, 0, stream>>>(H, src, dst, dinv, out, E);
    bn_stats_kernel<<<(N + 511) / 512, 256, 0, stream>>>(out, sum2, sq2, N);
    bn_final_kernel<<<1, 128, 0, stream>>>(sum2, sq2, mu2, rs2, N);
    bn_apply_kernel<<<(N * 32 + 255) / 256, 256, 0, stream>>>(out, gamma2, beta2, mu2, rs2, N);
}

// Round 2
// 980.718 us; speedup vs baseline: 3.3236x; 3.3236x over previous
//
#include <hip/hip_runtime.h>
#include <math.h>

#define BN_EPS 1e-5f

// ---------------- zero: cnt[N]=0, stats[1024]=0 ----------------
__global__ void zero_kernel(int* __restrict__ cnt, float* __restrict__ stats, int N) {
    int i = blockIdx.x * blockDim.x + threadIdx.x;
    if (i < N) cnt[i] = 0;
    if (i < 1024) stats[i] = 0.0f;
}

// ---------------- histogram over dst ----------------
__global__ void hist_kernel(const int* __restrict__ dst, int* __restrict__ cnt, int E) {
    int e = blockIdx.x * blockDim.x + threadIdx.x;
    if (e < E)
        __hip_atomic_fetch_add(&cnt[dst[e]], 1, __ATOMIC_RELAXED, __HIP_MEMORY_SCOPE_AGENT);
}

// dinv = rsqrt(deg+1)  (self loop)
__global__ void dinv_kernel(const int* __restrict__ cnt, float* __restrict__ dinv, int N) {
    int i = blockIdx.x * blockDim.x + threadIdx.x;
    if (i < N) dinv[i] = rsqrtf((float)cnt[i] + 1.0f);
}

// ---------------- exclusive scan (3 kernels), 1024 elems/block ----------------
__global__ __launch_bounds__(256) void scan_part(const int* __restrict__ cnt,
                                                 int* __restrict__ out,
                                                 int* __restrict__ blk, int N) {
    __shared__ int lds[256];
    int t = threadIdx.x;
    int base = blockIdx.x * 1024 + t * 4;
    int v[4];
    int s = 0;
#pragma unroll
    for (int i = 0; i < 4; ++i) { v[i] = (base + i < N) ? cnt[base + i] : 0; s += v[i]; }
    lds[t] = s;
    __syncthreads();
    for (int off = 1; off < 256; off <<= 1) {
        int x = (t >= off) ? lds[t - off] : 0;
        __syncthreads();
        lds[t] += x;
        __syncthreads();
    }
    int excl = lds[t] - s;
    if (t == 255) blk[blockIdx.x] = lds[255];
    int run = excl;
#pragma unroll
    for (int i = 0; i < 4; ++i) {
        if (base + i < N) out[base + i] = run;
        run += v[i];
    }
}

__global__ void scan_blk(int* __restrict__ blk, int nb) {
    if (threadIdx.x == 0) {
        int run = 0;
        for (int i = 0; i < nb; ++i) { int v = blk[i]; blk[i] = run; run += v; }
    }
}

__global__ void scan_add(int* __restrict__ rowptr, const int* __restrict__ blk,
                         int* __restrict__ cursor, int N) {
    int i = blockIdx.x * blockDim.x + threadIdx.x;
    if (i < N) {
        int v = rowptr[i] + blk[i >> 10];
        rowptr[i] = v;
        cursor[i] = v;
    }
}

// ---------------- fill sorted src by dst bucket ----------------
__global__ void fill_kernel(const int* __restrict__ src, const int* __restrict__ dst,
                            int* __restrict__ cursor, int* __restrict__ ssrc, int E) {
    int e = blockIdx.x * blockDim.x + threadIdx.x;
    if (e < E) {
        int d = dst[e];
        int pos = __hip_atomic_fetch_add(&cursor[d], 1, __ATOMIC_RELAXED, __HIP_MEMORY_SCOPE_AGENT);
        ssrc[pos] = src[e];
    }
}

// ---------------- Wc = proj_W @ W1  (256x256 @ 256x128) ----------------
__global__ void wc_kernel(const float* __restrict__ PW, const float* __restrict__ W1,
                          float* __restrict__ Wc) {
    int r = blockIdx.x;
    int c = threadIdx.x;
    float acc = 0.f;
    for (int k = 0; k < 256; ++k) acc = fmaf(PW[r * 256 + k], W1[k * 128 + c], acc);
    Wc[r * 128 + c] = acc;
}

__global__ void bc_kernel(const float* __restrict__ pb, const float* __restrict__ W1,
                          float* __restrict__ bc) {
    int c = threadIdx.x;
    float acc = 0.f;
    for (int k = 0; k < 256; ++k) acc = fmaf(pb[k], W1[k * 128 + c], acc);
    bc[c] = acc;
}

// ---------------- Hs = (op(X) @ W + bias) * dinv[row]; op = optional BN1+ReLU ----------------
template <int K, bool BN>
__global__ __launch_bounds__(128) void gemv_kernel(
    const float* __restrict__ X, const float* __restrict__ W,
    const float* __restrict__ bias, const float* __restrict__ dinv,
    float* __restrict__ H, int N,
    const float* __restrict__ gamma, const float* __restrict__ beta,
    const float* __restrict__ mu, const float* __restrict__ rstd)
{
    constexpr int ROWS = 8;
    constexpr int DOUT = 128;
    __shared__ float xs[ROWS][K];
    const int tid = threadIdx.x;
    const int r0 = blockIdx.x * ROWS;
    constexpr int K4 = K / 4;
    const float4* X4 = (const float4*)X;

    for (int i = tid; i < ROWS * K4; i += DOUT) {
        int row = i / K4;
        int k4  = i % K4;
        int gr  = r0 + row;
        float4 v = make_float4(0.f, 0.f, 0.f, 0.f);
        if (gr < N) v = X4[(size_t)gr * K4 + k4];
        if (BN) {
            int c = 4 * k4;
            float4 g  = *(const float4*)&gamma[c];
            float4 b  = *(const float4*)&beta[c];
            float4 m  = *(const float4*)&mu[c];
            float4 rs = *(const float4*)&rstd[c];
            v.x = fmaxf(fmaf(g.x * (v.x - m.x), rs.x, b.x), 0.f);
            v.y = fmaxf(fmaf(g.y * (v.y - m.y), rs.y, b.y), 0.f);
            v.z = fmaxf(fmaf(g.z * (v.z - m.z), rs.z, b.z), 0.f);
            v.w = fmaxf(fmaf(g.w * (v.w - m.w), rs.w, b.w), 0.f);
        }
        *(float4*)&xs[row][4 * k4] = v;
    }
    __syncthreads();

    float acc[ROWS];
#pragma unroll
    for (int r = 0; r < ROWS; ++r) acc[r] = 0.f;

    for (int k = 0; k < K; k += 4) {
        float4 xr[ROWS];
#pragma unroll
        for (int r = 0; r < ROWS; ++r) xr[r] = *(const float4*)&xs[r][k];
        float w0 = W[(k + 0) * DOUT + tid];
        float w1 = W[(k + 1) * DOUT + tid];
        float w2 = W[(k + 2) * DOUT + tid];
        float w3 = W[(k + 3) * DOUT + tid];
#pragma unroll
        for (int r = 0; r < ROWS; ++r) {
            acc[r] = fmaf(xr[r].x, w0, acc[r]);
            acc[r] = fmaf(xr[r].y, w1, acc[r]);
            acc[r] = fmaf(xr[r].z, w2, acc[r]);
            acc[r] = fmaf(xr[r].w, w3, acc[r]);
        }
    }

    float bb = bias ? bias[tid] : 0.f;
#pragma unroll
    for (int r = 0; r < ROWS; ++r) {
        int gr = r0 + r;
        if (gr < N) H[(size_t)gr * DOUT + tid] = (acc[r] + bb) * dinv[gr];
    }
}

// ---------------- gather-reduce aggregation (no atomics) ----------------
// out[d] = dinv[d] * (Hs[d] + sum_{s in N(d)} Hs[s]) + bias
// one wave per node, 2 channels per lane.
__global__ __launch_bounds__(256) void agg_gather_kernel(
    const float* __restrict__ Hs, const int* __restrict__ rowptr,
    const int* __restrict__ cnt, const int* __restrict__ ssrc,
    const float* __restrict__ dinv, const float* __restrict__ bias,
    float* __restrict__ Out, int N)
{
    int node = blockIdx.x * 4 + (threadIdx.x >> 6);
    if (node >= N) return;
    int lane = threadIdx.x & 63;
    const float2* H2 = (const float2*)Hs;
    size_t row = (size_t)node * 64 + lane;
    float2 a0 = H2[row];                       // self term
    float2 a1 = {0.f, 0.f}, a2 = {0.f, 0.f}, a3 = {0.f, 0.f};
    int start = rowptr[node];
    int num   = cnt[node];
    int j = 0;
    for (; j + 4 <= num; j += 4) {
        int s0 = ssrc[start + j + 0];
        int s1 = ssrc[start + j + 1];
        int s2 = ssrc[start + j + 2];
        int s3 = ssrc[start + j + 3];
        float2 v0 = H2[(size_t)s0 * 64 + lane];
        float2 v1 = H2[(size_t)s1 * 64 + lane];
        float2 v2 = H2[(size_t)s2 * 64 + lane];
        float2 v3 = H2[(size_t)s3 * 64 + lane];
        a0.x += v0.x; a0.y += v0.y;
        a1.x += v1.x; a1.y += v1.y;
        a2.x += v2.x; a2.y += v2.y;
        a3.x += v3.x; a3.y += v3.y;
    }
    for (; j < num; ++j) {
        int s = ssrc[start + j];
        float2 v = H2[(size_t)s * 64 + lane];
        a0.x += v.x; a0.y += v.y;
    }
    float di = dinv[node];
    float2 bb = ((const float2*)bias)[lane];
    float2 o;
    o.x = fmaf(a0.x + a1.x + a2.x + a3.x, di, bb.x);
    o.y = fmaf(a0.y + a1.y + a2.y + a3.y, di, bb.y);
    ((float2*)Out)[row] = o;
}

// ---------------- BN stats: per-column sum / sumsq ----------------
__global__ __launch_bounds__(256) void bn_stats_kernel(
    const float* __restrict__ A, float* __restrict__ sum, float* __restrict__ sq, int N)
{
    int c    = threadIdx.x & 127;
    int half = threadIdx.x >> 7;
    int r0   = blockIdx.x * 512;
    float s = 0.f, s2 = 0.f;
    for (int j = half; j < 512; j += 2) {
        int r = r0 + j;
        if (r < N) {
            float v = A[(size_t)r * 128 + c];
            s += v;
            s2 += v * v;
        }
    }
    __shared__ float ls[256], ls2[256];
    ls[threadIdx.x] = s;
    ls2[threadIdx.x] = s2;
    __syncthreads();
    if (threadIdx.x < 128) {
        float ts = ls[threadIdx.x] + ls[threadIdx.x + 128];
        float t2 = ls2[threadIdx.x] + ls2[threadIdx.x + 128];
        __hip_atomic_fetch_add(&sum[c], ts, __ATOMIC_RELAXED, __HIP_MEMORY_SCOPE_AGENT);
        __hip_atomic_fetch_add(&sq[c],  t2, __ATOMIC_RELAXED, __HIP_MEMORY_SCOPE_AGENT);
    }
}

__global__ void bn_final_kernel(const float* __restrict__ sum, const float* __restrict__ sq,
                                float* __restrict__ mu, float* __restrict__ rstd, int N) {
    int c = threadIdx.x;
    if (c < 128) {
        float m = sum[c] / (float)N;
        float v = sq[c] / (float)N - m * m;
        mu[c] = m;
        rstd[c] = rsqrtf(v + BN_EPS);
    }
}

// ---------------- final BN apply in-place on d_out ----------------
__global__ void bn_apply_kernel(float* __restrict__ A, const float* __restrict__ gamma,
                                const float* __restrict__ beta, const float* __restrict__ mu,
                                const float* __restrict__ rstd, int N) {
    int i = blockIdx.x * blockDim.x + threadIdx.x;   // float4 index
    if (i >= N * 32) return;
    int c4 = i & 31;
    float4 v  = ((float4*)A)[i];
    float4 g  = ((const float4*)gamma)[c4];
    float4 b  = ((const float4*)beta)[c4];
    float4 m  = ((const float4*)mu)[c4];
    float4 rs = ((const float4*)rstd)[c4];
    v.x = fmaf(g.x * (v.x - m.x), rs.x, b.x);
    v.y = fmaf(g.y * (v.y - m.y), rs.y, b.y);
    v.z = fmaf(g.z * (v.z - m.z), rs.z, b.z);
    v.w = fmaf(g.w * (v.w - m.w), rs.w, b.w);
    ((float4*)A)[i] = v;
}

extern "C" void kernel_launch(void* const* d_in, const int* in_sizes, int n_in,
                              void* d_out, int out_size, void* d_ws, size_t ws_size,
                              hipStream_t stream) {
    const float* e_prev = (const float*)d_in[0];
    const int*   edges  = (const int*)d_in[1];
    const float* proj_W = (const float*)d_in[2];
    const float* proj_b = (const float*)d_in[3];
    const float* W1     = (const float*)d_in[4];
    const float* b1     = (const float*)d_in[5];
    const float* gamma1 = (const float*)d_in[6];
    const float* beta1  = (const float*)d_in[7];
    const float* W2     = (const float*)d_in[8];
    const float* b2     = (const float*)d_in[9];
    const float* gamma2 = (const float*)d_in[10];
    const float* beta2  = (const float*)d_in[11];
    float* out = (float*)d_out;

    const int N = in_sizes[0] / 256;
    const int E = in_sizes[1] / 2;
    const int* src = edges;
    const int* dst = edges + E;
    const int NB = (N + 1023) / 1024;   // scan blocks

    char* ws = (char*)d_ws;
    const size_t NH = (size_t)N * 128;
    float* H      = (float*)ws;                        // [N,128] Hs (scaled h)
    int*   cnt    = (int*)(H + NH);                    // [N]
    int*   rowptr = cnt + N;                           // [N]
    int*   cursor = rowptr + N;                        // [N]
    int*   ssrc   = cursor + N;                        // [E]
    int*   blk    = ssrc + E;                          // [NB]
    float* dinv   = (float*)(blk + ((NB + 255) & ~255)); // [N]
    float* Wc     = dinv + N;                          // [256*128]
    float* bc     = Wc + 256 * 128;                    // [128]
    float* stats  = bc + 128;                          // [1024]
    float* sum1 = stats,       *sq1 = stats + 128, *mu1 = stats + 256, *rs1 = stats + 384;
    float* sum2 = stats + 512, *sq2 = stats + 640, *mu2 = stats + 768, *rs2 = stats + 896;

    // ---- graph preprocessing: degree + CSR by dst ----
    zero_kernel<<<(N + 255) / 256, 256, 0, stream>>>(cnt, stats, N);
    hist_kernel<<<(E + 255) / 256, 256, 0, stream>>>(dst, cnt, E);
    dinv_kernel<<<(N + 255) / 256, 256, 0, stream>>>(cnt, dinv, N);
    scan_part<<<NB, 256, 0, stream>>>(cnt, rowptr, blk, N);
    scan_blk<<<1, 64, 0, stream>>>(blk, NB);
    scan_add<<<(N + 255) / 256, 256, 0, stream>>>(rowptr, blk, cursor, N);
    fill_kernel<<<(E + 255) / 256, 256, 0, stream>>>(src, dst, cursor, ssrc, E);

    // ---- folded weights ----
    wc_kernel<<<256, 128, 0, stream>>>(proj_W, W1, Wc);
    bc_kernel<<<1, 128, 0, stream>>>(proj_b, W1, bc);

    // ---- layer 1: Hs1 = (e_prev @ Wc + bc) * dinv ; A1 (in d_out) = gather ----
    gemv_kernel<256, false><<<(N + 7) / 8, 128, 0, stream>>>(
        e_prev, Wc, bc, dinv, H, N, nullptr, nullptr, nullptr, nullptr);
    agg_gather_kernel<<<(N + 3) / 4, 256, 0, stream>>>(H, rowptr, cnt, ssrc, dinv, b1, out, N);
    bn_stats_kernel<<<(N + 511) / 512, 256, 0, stream>>>(out, sum1, sq1, N);
    bn_final_kernel<<<1, 128, 0, stream>>>(sum1, sq1, mu1, rs1, N);

    // ---- layer 2: Hs2 = relu(bn1(A1)) @ W2 * dinv ; out = gather ----
    gemv_kernel<128, true><<<(N + 7) / 8, 128, 0, stream>>>(
        out, W2, nullptr, dinv, H, N, gamma1, beta1, mu1, rs1);
    agg_gather_kernel<<<(N + 3) / 4, 256, 0, stream>>>(H, rowptr, cnt, ssrc, dinv, b2, out, N);
    bn_stats_kernel<<<(N + 511) / 512, 256, 0, stream>>>(out, sum2, sq2, N);
    bn_final_kernel<<<1, 128, 0, stream>>>(sum2, sq2, mu2, rs2, N);
    bn_apply_kernel<<<(N * 32 + 255) / 256, 256, 0, stream>>>(out, gamma2, beta2, mu2, rs2, N);
}

// Round 3
// 782.941 us; speedup vs baseline: 4.1632x; 1.2526x over previous
//
#include <hip/hip_runtime.h>
#include <hip/hip_bf16.h>
#include <math.h>

#define BN_EPS 1e-5f

typedef __attribute__((ext_vector_type(8))) short short8;
typedef __attribute__((ext_vector_type(4))) float floatx4;

// ---------------- zero: cnt[N]=0, stats[1024]=0 ----------------
__global__ void zero_kernel(int* __restrict__ cnt, float* __restrict__ stats, int N) {
    int i = blockIdx.x * blockDim.x + threadIdx.x;
    if (i < N) cnt[i] = 0;
    if (i < 1024) stats[i] = 0.0f;
}

// ---------------- histogram over dst ----------------
__global__ void hist_kernel(const int* __restrict__ dst, int* __restrict__ cnt, int E) {
    int e = blockIdx.x * blockDim.x + threadIdx.x;
    if (e < E)
        __hip_atomic_fetch_add(&cnt[dst[e]], 1, __ATOMIC_RELAXED, __HIP_MEMORY_SCOPE_AGENT);
}

// dinv = rsqrt(deg+1)  (self loop)
__global__ void dinv_kernel(const int* __restrict__ cnt, float* __restrict__ dinv, int N) {
    int i = blockIdx.x * blockDim.x + threadIdx.x;
    if (i < N) dinv[i] = rsqrtf((float)cnt[i] + 1.0f);
}

// ---------------- exclusive scan (3 kernels), 1024 elems/block ----------------
__global__ __launch_bounds__(256) void scan_part(const int* __restrict__ cnt,
                                                 int* __restrict__ out,
                                                 int* __restrict__ blk, int N) {
    __shared__ int lds[256];
    int t = threadIdx.x;
    int base = blockIdx.x * 1024 + t * 4;
    int v[4];
    int s = 0;
#pragma unroll
    for (int i = 0; i < 4; ++i) { v[i] = (base + i < N) ? cnt[base + i] : 0; s += v[i]; }
    lds[t] = s;
    __syncthreads();
    for (int off = 1; off < 256; off <<= 1) {
        int x = (t >= off) ? lds[t - off] : 0;
        __syncthreads();
        lds[t] += x;
        __syncthreads();
    }
    int excl = lds[t] - s;
    if (t == 255) blk[blockIdx.x] = lds[255];
    int run = excl;
#pragma unroll
    for (int i = 0; i < 4; ++i) {
        if (base + i < N) out[base + i] = run;
        run += v[i];
    }
}

__global__ void scan_blk(int* __restrict__ blk, int nb) {
    if (threadIdx.x == 0) {
        int run = 0;
        for (int i = 0; i < nb; ++i) { int v = blk[i]; blk[i] = run; run += v; }
    }
}

__global__ void scan_add(int* __restrict__ rowptr, const int* __restrict__ blk,
                         int* __restrict__ cursor, int N) {
    int i = blockIdx.x * blockDim.x + threadIdx.x;
    if (i < N) {
        int v = rowptr[i] + blk[i >> 10];
        rowptr[i] = v;
        cursor[i] = v;
    }
}

// ---------------- fill sorted src by dst bucket ----------------
__global__ void fill_kernel(const int* __restrict__ src, const int* __restrict__ dst,
                            int* __restrict__ cursor, int* __restrict__ ssrc, int E) {
    int e = blockIdx.x * blockDim.x + threadIdx.x;
    if (e < E) {
        int d = dst[e];
        int pos = __hip_atomic_fetch_add(&cursor[d], 1, __ATOMIC_RELAXED, __HIP_MEMORY_SCOPE_AGENT);
        ssrc[pos] = src[e];
    }
}

// ---------------- Wc = proj_W @ W1  (256x256 @ 256x128) ----------------
__global__ void wc_kernel(const float* __restrict__ PW, const float* __restrict__ W1,
                          float* __restrict__ Wc) {
    int r = blockIdx.x;
    int c = threadIdx.x;
    float acc = 0.f;
    for (int k = 0; k < 256; ++k) acc = fmaf(PW[r * 256 + k], W1[k * 128 + c], acc);
    Wc[r * 128 + c] = acc;
}

__global__ void bc_kernel(const float* __restrict__ pb, const float* __restrict__ W1,
                          float* __restrict__ bc) {
    int c = threadIdx.x;
    float acc = 0.f;
    for (int k = 0; k < 256; ++k) acc = fmaf(pb[k], W1[k * 128 + c], acc);
    bc[c] = acc;
}

// ---------------- pack W [K x 128] fp32 -> fragment-order bf16 ----------------
// Wf element t = ((kc*8 + ct)*64 + lane)*8 + j  holds  W[kc*32 + (lane>>4)*8 + j][ct*16 + (lane&15)]
template <int K>
__global__ void packW_kernel(const float* __restrict__ W, __hip_bfloat16* __restrict__ Wf) {
    int t = blockIdx.x * 256 + threadIdx.x;
    if (t >= (K / 32) * 8 * 64 * 8) return;
    int j    = t & 7;
    int lane = (t >> 3) & 63;
    int ct   = (t >> 9) & 7;
    int kc   = t >> 12;
    int k = kc * 32 + ((lane >> 4) & 3) * 8 + j;
    int c = ct * 16 + (lane & 15);
    Wf[t] = __float2bfloat16(W[k * 128 + c]);
}

__device__ inline short8 cvt8(float4 a, float4 b) {
    __hip_bfloat162 p0 = __float22bfloat162_rn(make_float2(a.x, a.y));
    __hip_bfloat162 p1 = __float22bfloat162_rn(make_float2(a.z, a.w));
    __hip_bfloat162 p2 = __float22bfloat162_rn(make_float2(b.x, b.y));
    __hip_bfloat162 p3 = __float22bfloat162_rn(make_float2(b.z, b.w));
    union { short8 s; __hip_bfloat162 h[4]; } u;
    u.h[0] = p0; u.h[1] = p1; u.h[2] = p2; u.h[3] = p3;
    return u.s;
}

// ---------------- MFMA GEMM: Hs(bf16) = (op(X[N,K]) @ W[K,128] + bias) * dinv[row] ----------------
// op = optional BN+ReLU (scale/shift per k-channel). No LDS, no barriers.
// block = 256 thr (4 waves), each wave 32 rows (2 row-tiles of 16), 8 c-tiles of 16.
template <int K, bool BN>
__global__ __launch_bounds__(256) void mfma_gemm(
    const float* __restrict__ X, const short* __restrict__ Wf,
    const float* __restrict__ bias, const float* __restrict__ dinv,
    const float* __restrict__ scale, const float* __restrict__ shift,
    __hip_bfloat16* __restrict__ Hs, int N)
{
    const int wave = threadIdx.x >> 6;
    const int lane = threadIdx.x & 63;
    const int l16  = lane & 15;
    const int q    = lane >> 4;            // 0..3
    const int r0   = blockIdx.x * 128 + wave * 32;

    const int ra0 = min(r0 + l16, N - 1);
    const int ra1 = min(r0 + 16 + l16, N - 1);
    const float* pA0 = X + (size_t)ra0 * K + q * 8;
    const float* pA1 = X + (size_t)ra1 * K + q * 8;
    const short8* WF = (const short8*)Wf;

    floatx4 acc[2][8];
#pragma unroll
    for (int rt = 0; rt < 2; ++rt)
#pragma unroll
        for (int ct = 0; ct < 8; ++ct) { acc[rt][ct][0] = 0.f; acc[rt][ct][1] = 0.f; acc[rt][ct][2] = 0.f; acc[rt][ct][3] = 0.f; }

#pragma unroll
    for (int kc = 0; kc < K / 32; ++kc) {
        short8 b[8];
#pragma unroll
        for (int ct = 0; ct < 8; ++ct) b[ct] = WF[(kc * 8 + ct) * 64 + lane];

        float4 x00 = *(const float4*)(pA0 + kc * 32);
        float4 x01 = *(const float4*)(pA0 + kc * 32 + 4);
        float4 x10 = *(const float4*)(pA1 + kc * 32);
        float4 x11 = *(const float4*)(pA1 + kc * 32 + 4);
        if (BN) {
            float4 sc0 = *(const float4*)(scale + kc * 32 + q * 8);
            float4 sc1 = *(const float4*)(scale + kc * 32 + q * 8 + 4);
            float4 sh0 = *(const float4*)(shift + kc * 32 + q * 8);
            float4 sh1 = *(const float4*)(shift + kc * 32 + q * 8 + 4);
            x00.x = fmaxf(fmaf(x00.x, sc0.x, sh0.x), 0.f);
            x00.y = fmaxf(fmaf(x00.y, sc0.y, sh0.y), 0.f);
            x00.z = fmaxf(fmaf(x00.z, sc0.z, sh0.z), 0.f);
            x00.w = fmaxf(fmaf(x00.w, sc0.w, sh0.w), 0.f);
            x01.x = fmaxf(fmaf(x01.x, sc1.x, sh1.x), 0.f);
            x01.y = fmaxf(fmaf(x01.y, sc1.y, sh1.y), 0.f);
            x01.z = fmaxf(fmaf(x01.z, sc1.z, sh1.z), 0.f);
            x01.w = fmaxf(fmaf(x01.w, sc1.w, sh1.w), 0.f);
            x10.x = fmaxf(fmaf(x10.x, sc0.x, sh0.x), 0.f);
            x10.y = fmaxf(fmaf(x10.y, sc0.y, sh0.y), 0.f);
            x10.z = fmaxf(fmaf(x10.z, sc0.z, sh0.z), 0.f);
            x10.w = fmaxf(fmaf(x10.w, sc0.w, sh0.w), 0.f);
            x11.x = fmaxf(fmaf(x11.x, sc1.x, sh1.x), 0.f);
            x11.y = fmaxf(fmaf(x11.y, sc1.y, sh1.y), 0.f);
            x11.z = fmaxf(fmaf(x11.z, sc1.z, sh1.z), 0.f);
            x11.w = fmaxf(fmaf(x11.w, sc1.w, sh1.w), 0.f);
        }
        short8 a0 = cvt8(x00, x01);
        short8 a1 = cvt8(x10, x11);
#pragma unroll
        for (int ct = 0; ct < 8; ++ct) {
            acc[0][ct] = __builtin_amdgcn_mfma_f32_16x16x32_bf16(a0, b[ct], acc[0][ct], 0, 0, 0);
            acc[1][ct] = __builtin_amdgcn_mfma_f32_16x16x32_bf16(a1, b[ct], acc[1][ct], 0, 0, 0);
        }
    }

    float bb[8];
#pragma unroll
    for (int ct = 0; ct < 8; ++ct) bb[ct] = bias ? bias[ct * 16 + l16] : 0.f;

#pragma unroll
    for (int rt = 0; rt < 2; ++rt) {
        int rbase = r0 + rt * 16 + q * 4;
        float dv[4];
#pragma unroll
        for (int i = 0; i < 4; ++i) dv[i] = dinv[min(rbase + i, N - 1)];
#pragma unroll
        for (int ct = 0; ct < 8; ++ct) {
#pragma unroll
            for (int i = 0; i < 4; ++i) {
                int row = rbase + i;
                if (row < N)
                    Hs[(size_t)row * 128 + ct * 16 + l16] =
                        __float2bfloat16((acc[rt][ct][i] + bb[ct]) * dv[i]);
            }
        }
    }
}

// ---------------- gather-reduce aggregation over bf16 Hs ----------------
// out[d] = dinv[d] * (Hs[d] + sum_{s in N(d)} Hs[s]) + bias
__device__ inline void bfacc(unsigned u, float& x, float& y) {
    x += __uint_as_float(u << 16);
    y += __uint_as_float(u & 0xffff0000u);
}

__global__ __launch_bounds__(256) void agg_gather_kernel(
    const unsigned* __restrict__ H2u, const int* __restrict__ rowptr,
    const int* __restrict__ cnt, const int* __restrict__ ssrc,
    const float* __restrict__ dinv, const float* __restrict__ bias,
    float* __restrict__ Out, int N)
{
    int node = blockIdx.x * 4 + (threadIdx.x >> 6);
    if (node >= N) return;
    int lane = threadIdx.x & 63;
    size_t row = (size_t)node * 64 + lane;
    float a0x = 0.f, a0y = 0.f, a1x = 0.f, a1y = 0.f;
    float a2x = 0.f, a2y = 0.f, a3x = 0.f, a3y = 0.f;
    bfacc(H2u[row], a0x, a0y);                  // self term
    int start = rowptr[node];
    int num   = cnt[node];
    int j = 0;
    for (; j + 4 <= num; j += 4) {
        int s0 = ssrc[start + j + 0];
        int s1 = ssrc[start + j + 1];
        int s2 = ssrc[start + j + 2];
        int s3 = ssrc[start + j + 3];
        unsigned u0 = H2u[(size_t)s0 * 64 + lane];
        unsigned u1 = H2u[(size_t)s1 * 64 + lane];
        unsigned u2 = H2u[(size_t)s2 * 64 + lane];
        unsigned u3 = H2u[(size_t)s3 * 64 + lane];
        bfacc(u0, a0x, a0y);
        bfacc(u1, a1x, a1y);
        bfacc(u2, a2x, a2y);
        bfacc(u3, a3x, a3y);
    }
    for (; j < num; ++j) {
        bfacc(H2u[(size_t)ssrc[start + j] * 64 + lane], a0x, a0y);
    }
    float di = dinv[node];
    float2 bb = ((const float2*)bias)[lane];
    float2 o;
    o.x = fmaf(a0x + a1x + a2x + a3x, di, bb.x);
    o.y = fmaf(a0y + a1y + a2y + a3y, di, bb.y);
    ((float2*)Out)[row] = o;
}

// ---------------- BN stats: per-column sum / sumsq ----------------
__global__ __launch_bounds__(256) void bn_stats_kernel(
    const float* __restrict__ A, float* __restrict__ sum, float* __restrict__ sq, int N)
{
    int c    = threadIdx.x & 127;
    int half = threadIdx.x >> 7;
    int r0   = blockIdx.x * 512;
    float s = 0.f, s2 = 0.f;
    for (int j = half; j < 512; j += 2) {
        int r = r0 + j;
        if (r < N) {
            float v = A[(size_t)r * 128 + c];
            s += v;
            s2 += v * v;
        }
    }
    __shared__ float ls[256], ls2[256];
    ls[threadIdx.x] = s;
    ls2[threadIdx.x] = s2;
    __syncthreads();
    if (threadIdx.x < 128) {
        float ts = ls[threadIdx.x] + ls[threadIdx.x + 128];
        float t2 = ls2[threadIdx.x] + ls2[threadIdx.x + 128];
        __hip_atomic_fetch_add(&sum[c], ts, __ATOMIC_RELAXED, __HIP_MEMORY_SCOPE_AGENT);
        __hip_atomic_fetch_add(&sq[c],  t2, __ATOMIC_RELAXED, __HIP_MEMORY_SCOPE_AGENT);
    }
}

// also emits fused scale/shift (gamma*rstd, beta-mu*scale) when requested
__global__ void bn_final_kernel(const float* __restrict__ sum, const float* __restrict__ sq,
                                float* __restrict__ mu, float* __restrict__ rstd,
                                const float* __restrict__ gamma, const float* __restrict__ beta,
                                float* __restrict__ scale, float* __restrict__ shift, int N) {
    int c = threadIdx.x;
    if (c < 128) {
        float m = sum[c] / (float)N;
        float v = sq[c] / (float)N - m * m;
        float rs = rsqrtf(v + BN_EPS);
        mu[c] = m;
        rstd[c] = rs;
        if (scale) {
            float sc = gamma[c] * rs;
            scale[c] = sc;
            shift[c] = fmaf(-m, sc, beta[c]);
        }
    }
}

// ---------------- final BN apply in-place on d_out ----------------
__global__ void bn_apply_kernel(float* __restrict__ A, const float* __restrict__ gamma,
                                const float* __restrict__ beta, const float* __restrict__ mu,
                                const float* __restrict__ rstd, int N) {
    int i = blockIdx.x * blockDim.x + threadIdx.x;   // float4 index
    if (i >= N * 32) return;
    int c4 = i & 31;
    float4 v  = ((float4*)A)[i];
    float4 g  = ((const float4*)gamma)[c4];
    float4 b  = ((const float4*)beta)[c4];
    float4 m  = ((const float4*)mu)[c4];
    float4 rs = ((const float4*)rstd)[c4];
    v.x = fmaf(g.x * (v.x - m.x), rs.x, b.x);
    v.y = fmaf(g.y * (v.y - m.y), rs.y, b.y);
    v.z = fmaf(g.z * (v.z - m.z), rs.z, b.z);
    v.w = fmaf(g.w * (v.w - m.w), rs.w, b.w);
    ((float4*)A)[i] = v;
}

extern "C" void kernel_launch(void* const* d_in, const int* in_sizes, int n_in,
                              void* d_out, int out_size, void* d_ws, size_t ws_size,
                              hipStream_t stream) {
    const float* e_prev = (const float*)d_in[0];
    const int*   edges  = (const int*)d_in[1];
    const float* proj_W = (const float*)d_in[2];
    const float* proj_b = (const float*)d_in[3];
    const float* W1     = (const float*)d_in[4];
    const float* b1     = (const float*)d_in[5];
    const float* gamma1 = (const float*)d_in[6];
    const float* beta1  = (const float*)d_in[7];
    const float* W2     = (const float*)d_in[8];
    const float* b2     = (const float*)d_in[9];
    const float* gamma2 = (const float*)d_in[10];
    const float* beta2  = (const float*)d_in[11];
    float* out = (float*)d_out;

    const int N = in_sizes[0] / 256;
    const int E = in_sizes[1] / 2;
    const int* src = edges;
    const int* dst = edges + E;
    const int NB = (N + 1023) / 1024;

    char* p = (char*)d_ws;
    const size_t NH = (size_t)N * 128;
    __hip_bfloat16* Hs = (__hip_bfloat16*)p;  p += NH * 2;
    int* cnt    = (int*)p;  p += (size_t)N * 4;
    int* rowptr = (int*)p;  p += (size_t)N * 4;
    int* cursor = (int*)p;  p += (size_t)N * 4;
    int* ssrc   = (int*)p;  p += (size_t)E * 4;
    int* blk    = (int*)p;  p += ((NB + 255) & ~255) * 4;
    float* dinv = (float*)p; p += (size_t)N * 4;
    float* Wc   = (float*)p; p += 256 * 128 * 4;
    float* bc   = (float*)p; p += 128 * 4;
    float* stats = (float*)p; p += 1536 * 4;
    __hip_bfloat16* Wf1 = (__hip_bfloat16*)p; p += 256 * 128 * 2;
    __hip_bfloat16* Wf2 = (__hip_bfloat16*)p; p += 128 * 128 * 2;
    float* sum1 = stats,       *sq1 = stats + 128, *mu1 = stats + 256, *rs1 = stats + 384;
    float* sum2 = stats + 512, *sq2 = stats + 640, *mu2 = stats + 768, *rs2 = stats + 896;
    float* scale1 = stats + 1024, *shift1 = stats + 1152;

    // ---- graph preprocessing: degree + CSR by dst ----
    zero_kernel<<<(N + 255) / 256, 256, 0, stream>>>(cnt, stats, N);
    hist_kernel<<<(E + 255) / 256, 256, 0, stream>>>(dst, cnt, E);
    dinv_kernel<<<(N + 255) / 256, 256, 0, stream>>>(cnt, dinv, N);
    scan_part<<<NB, 256, 0, stream>>>(cnt, rowptr, blk, N);
    scan_blk<<<1, 64, 0, stream>>>(blk, NB);
    scan_add<<<(N + 255) / 256, 256, 0, stream>>>(rowptr, blk, cursor, N);
    fill_kernel<<<(E + 255) / 256, 256, 0, stream>>>(src, dst, cursor, ssrc, E);

    // ---- folded weights + fragment packs ----
    wc_kernel<<<256, 128, 0, stream>>>(proj_W, W1, Wc);
    bc_kernel<<<1, 128, 0, stream>>>(proj_b, W1, bc);
    packW_kernel<256><<<(256 * 128 + 255) / 256, 256, 0, stream>>>(Wc, Wf1);
    packW_kernel<128><<<(128 * 128 + 255) / 256, 256, 0, stream>>>(W2, Wf2);

    const int gemm_grid = (N + 127) / 128;

    // ---- layer 1 ----
    mfma_gemm<256, false><<<gemm_grid, 256, 0, stream>>>(
        e_prev, (const short*)Wf1, bc, dinv, nullptr, nullptr, Hs, N);
    agg_gather_kernel<<<(N + 3) / 4, 256, 0, stream>>>(
        (const unsigned*)Hs, rowptr, cnt, ssrc, dinv, b1, out, N);
    bn_stats_kernel<<<(N + 511) / 512, 256, 0, stream>>>(out, sum1, sq1, N);
    bn_final_kernel<<<1, 128, 0, stream>>>(sum1, sq1, mu1, rs1, gamma1, beta1, scale1, shift1, N);

    // ---- layer 2 ----
    mfma_gemm<128, true><<<gemm_grid, 256, 0, stream>>>(
        out, (const short*)Wf2, nullptr, dinv, scale1, shift1, Hs, N);
    agg_gather_kernel<<<(N + 3) / 4, 256, 0, stream>>>(
        (const unsigned*)Hs, rowptr, cnt, ssrc, dinv, b2, out, N);
    bn_stats_kernel<<<(N + 511) / 512, 256, 0, stream>>>(out, sum2, sq2, N);
    bn_final_kernel<<<1, 128, 0, stream>>>(sum2, sq2, mu2, rs2, nullptr, nullptr, nullptr, nullptr, N);
    bn_apply_kernel<<<(N * 32 + 255) / 256, 256, 0, stream>>>(out, gamma2, beta2, mu2, rs2, N);
}